// Round 14
// baseline (146.382 us; speedup 1.0000x reference)
//
#include <hip/hip_runtime.h>

// ---- problem constants ----
#define CIN   16
#define COUTC 8
#define HIN   8
#define WINW  8
#define SST   2
#define PPD   1
#define HOUTC 16
#define WOUTC 16
#define IN_F  2304   // CIN*3*3*4*4
#define OUT_F 4608   // COUT*3*3*8*8
#define BATCH 64

// ---- gemm decomposition (R9 geometry: best measured, 104.2 us) ----
// Grid = (OUT_F/48) * OS = 96*8 = 768 = EXACTLY 3 blocks/CU (perfect balance).
// os = blockIdx % 8 == XCD (round-robin dispatch) -> act chunk L2-pinned.
#define OS    8             // K-splits
#define FC    (IN_F / OS)   // 288 f per block (longest per-lane weight stream)
#define SF    16            // f's per LDS subtile
#define NSUB  (FC / SF)     // 18 subtiles
#define NWAVE 3             // waves per block (48 o-rows)

typedef __bf16 bf16x8 __attribute__((ext_vector_type(8)));
typedef float  f32x4  __attribute__((ext_vector_type(4)));

// uniform knot grid: g[t] = (t-3)*0.4 - 1
__device__ __forceinline__ float gridv(int t) {
    return (float)(t - 3) * 0.4f - 1.0f;
}

// async global->LDS: per-lane global src, wave-uniform LDS base (+lane*16 by HW)
__device__ __forceinline__ void gload_lds16(const float* g, float* l) {
    __builtin_amdgcn_global_load_lds(
        (const __attribute__((address_space(1))) unsigned int*)g,
        (__attribute__((address_space(3))) unsigned int*)l, 16, 0, 0);
}

// ---------------------------------------------------------------
// prep: u = unfold(x); activations bf16 packed in lane-linear
// MFMA B-fragment chunks (1KB per (f-group, b-group) chunk).
//   spline: chunk C = (f>>2)*4 + (b>>4); slot = (f&3)*16 + (b&15)
//   base:   chunk C = (f>>5)*4 + (b>>4); slot = ((f>>3)&3)*16 + (b&15), elem f&7
// ---------------------------------------------------------------
__global__ __launch_bounds__(256) void prep_kernel(const float* __restrict__ x,
                                                   __bf16* __restrict__ Abb,
                                                   __bf16* __restrict__ Bsb) {
    int tid = blockIdx.x * 256 + threadIdx.x;   // tid = f*64 + b
    if (tid >= IN_F * BATCH) return;
    int f = tid >> 6, b = tid & 63;
    int ckk = f >> 4, s = f & 15;
    int c = ckk / 9, r = ckk % 9;
    int ki = r / 3, kj = r % 3;
    int oh = s >> 2, ow = s & 3;
    int h = ki + oh * SST - PPD;
    int w = kj + ow * SST - PPD;
    float u = 0.0f;
    if (h >= 0 && h < HIN && w >= 0 && w < WINW)
        u = x[((b * CIN + c) * HIN + h) * WINW + w];

    // base activation (silu)
    {
        size_t idx = ((size_t)((f >> 5) * 4 + (b >> 4))) * 512
                   + (((f >> 3) & 3) * 16 + (b & 15)) * 8 + (f & 7);
        Abb[idx] = (__bf16)(u / (1.0f + __expf(-u)));
    }

    // degree-3 B-spline bases (Cox-de Boor, matches reference)
    float bs[11];
#pragma unroll
    for (int t = 0; t < 11; ++t)
        bs[t] = (u >= gridv(t) && u < gridv(t + 1)) ? 1.0f : 0.0f;
#pragma unroll
    for (int k = 1; k <= 3; ++k) {
#pragma unroll
        for (int i = 0; i < 11; ++i) {
            if (i < 11 - k) {
                float g_i  = gridv(i);
                float g_ik = gridv(i + k);
                float g_i1 = gridv(i + 1);
                float g_k1 = gridv(i + k + 1);
                bs[i] = (u - g_i) / (g_ik - g_i) * bs[i]
                      + (g_k1 - u) / (g_k1 - g_i1) * bs[i + 1];
            }
        }
    }
    bf16x8 v;
#pragma unroll
    for (int t = 0; t < 8; ++t) v[t] = (__bf16)bs[t];
    size_t frag = ((size_t)((f >> 2) * 4 + (b >> 4))) * 64
                + (f & 3) * 16 + (b & 15);
    ((bf16x8*)Bsb)[frag] = v;
}

// ---------------------------------------------------------------
// MFMA GEMM. Weights fp32 + spline_scaler streamed direct to registers
// (cvt bf16 in-register); activations staged to LDS (double-buffered).
// Block: 3 waves x 16 DISJOINT o-rows = 48 o's, shared K-chunk of FC f's.
// Wave: 16 o x 64 b. No cross-wave reduce. Grid 768 = 3 blocks/CU; os==XCD.
// sc: per K-step each lane loads its row's 16B sc-quartet (shared by 4
// lg-siblings -> coalesced 16x16B) and selects component lg via cndmask
// (static select, rule #20). No sc LDS -> no 8-way-conflicted ds_read.
// ---------------------------------------------------------------
__global__ __launch_bounds__(192, 2) void gemm_kernel(
    const float* __restrict__ Wb,    // (OUT_F, IN_F)
    const float* __restrict__ Ws,    // (OUT_F, IN_F, 8)
    const float* __restrict__ Sc,    // (OUT_F, IN_F)
    const __bf16* __restrict__ Abb,  // base B-frags (packed chunks)
    const __bf16* __restrict__ Bsb,  // spline B-frags (packed chunks)
    float* __restrict__ partial)     // (OS, OUT_F, 64)
{
    __shared__ __align__(16) char smem[2 * 16384];   // 32 KB act double-buffer

    const int tid  = threadIdx.x;
    const int lane = tid & 63;
    const int wv   = tid >> 6;       // 0..2
    const int lr   = lane & 15;      // o-in-wave-tile / b-in-frag
    const int lg   = lane >> 4;      // k-group
    const int ot = blockIdx.x / OS;
    const int os = blockIdx.x % OS;  // == XCD under round-robin dispatch
    const int o0 = ot * 48;
    const int f0 = os * FC;
    const int o  = o0 + wv * 16 + lr;   // this lane's weight row

    f32x4 acc0 = {0.f,0.f,0.f,0.f}, acc1 = {0.f,0.f,0.f,0.f};
    f32x4 acc2 = {0.f,0.f,0.f,0.f}, acc3 = {0.f,0.f,0.f,0.f};

    // ---- stage act subtile t (16 KB): 16 x 1KB instrs split over 3 waves ----
    auto stage_act = [&](int t, int pb) {
        const char* src = (const char*)Bsb + (size_t)(f0 + t * SF) * 1024;
        char* dst = smem + pb * 16384;
        for (int i = wv; i < 16; i += NWAVE)
            gload_lds16((const float*)(src + i * 1024) + lane * 4,
                        (float*)(dst + i * 1024));
    };

    const float* wp  = Ws + ((size_t)o * IN_F + f0 + lg) * 8;
    const float* scp = Sc + (size_t)o * IN_F + f0;

    stage_act(0, 0);
    __syncthreads();

    for (int t = 0; t < NSUB; ++t) {
        const int pb = t & 1;
        if (t + 1 < NSUB) stage_act(t + 1, pb ^ 1);

        const char* ab = smem + pb * 16384;
#pragma unroll
        for (int s = 0; s < SF / 4; ++s) {          // 4 K-steps
            float4 w0 = *(const float4*)(wp + (size_t)(t * SF + s * 4) * 8);
            float4 w1 = *(const float4*)(wp + (size_t)(t * SF + s * 4) * 8 + 4);
            float4 s4 = *(const float4*)(scp + t * SF + s * 4);
            float  sc = (lg & 2) ? ((lg & 1) ? s4.w : s4.z)
                                 : ((lg & 1) ? s4.y : s4.x);
            bf16x8 b0 = *(const bf16x8*)(ab + s * 4096 +    0 + lane * 16);
            bf16x8 b1 = *(const bf16x8*)(ab + s * 4096 + 1024 + lane * 16);
            bf16x8 b2 = *(const bf16x8*)(ab + s * 4096 + 2048 + lane * 16);
            bf16x8 b3 = *(const bf16x8*)(ab + s * 4096 + 3072 + lane * 16);
            bf16x8 af;
            af[0] = (__bf16)(w0.x * sc); af[1] = (__bf16)(w0.y * sc);
            af[2] = (__bf16)(w0.z * sc); af[3] = (__bf16)(w0.w * sc);
            af[4] = (__bf16)(w1.x * sc); af[5] = (__bf16)(w1.y * sc);
            af[6] = (__bf16)(w1.z * sc); af[7] = (__bf16)(w1.w * sc);
            acc0 = __builtin_amdgcn_mfma_f32_16x16x32_bf16(af, b0, acc0, 0, 0, 0);
            acc1 = __builtin_amdgcn_mfma_f32_16x16x32_bf16(af, b1, acc1, 0, 0, 0);
            acc2 = __builtin_amdgcn_mfma_f32_16x16x32_bf16(af, b2, acc2, 0, 0, 0);
            acc3 = __builtin_amdgcn_mfma_f32_16x16x32_bf16(af, b3, acc3, 0, 0, 0);
        }
        __syncthreads();   // drains stage(t+1), guards buffer reuse
    }

    // ---- base GEMM: FC/32 = 9 K-steps, acts direct from global (L2-hot) ----
    const float*  wbp = Wb + (size_t)o * IN_F + f0 + lg * 8;
    const bf16x8* ap  = (const bf16x8*)Abb + ((size_t)f0 >> 5) * 256 + lane;
#pragma unroll
    for (int s = 0; s < FC / 32; ++s) {
        float4 w0 = *(const float4*)(wbp + s * 32);
        float4 w1 = *(const float4*)(wbp + s * 32 + 4);
        bf16x8 b0 = ap[s * 256 +   0];
        bf16x8 b1 = ap[s * 256 +  64];
        bf16x8 b2 = ap[s * 256 + 128];
        bf16x8 b3 = ap[s * 256 + 192];
        bf16x8 af;
        af[0] = (__bf16)w0.x; af[1] = (__bf16)w0.y;
        af[2] = (__bf16)w0.z; af[3] = (__bf16)w0.w;
        af[4] = (__bf16)w1.x; af[5] = (__bf16)w1.y;
        af[6] = (__bf16)w1.z; af[7] = (__bf16)w1.w;
        acc0 = __builtin_amdgcn_mfma_f32_16x16x32_bf16(af, b0, acc0, 0, 0, 0);
        acc1 = __builtin_amdgcn_mfma_f32_16x16x32_bf16(af, b1, acc1, 0, 0, 0);
        acc2 = __builtin_amdgcn_mfma_f32_16x16x32_bf16(af, b2, acc2, 0, 0, 0);
        acc3 = __builtin_amdgcn_mfma_f32_16x16x32_bf16(af, b3, acc3, 0, 0, 0);
    }

    // ---- epilogue: waves own disjoint o's -> direct coalesced store ----
    // D layout: lane holds D[lg*4 + r][lr]; b = j*16 + lr
#pragma unroll
    for (int r = 0; r < 4; ++r) {
        const size_t row = (size_t)os * OUT_F + o0 + wv * 16 + lg * 4 + r;
        partial[row * 64 +  0 + lr] = acc0[r];
        partial[row * 64 + 16 + lr] = acc1[r];
        partial[row * 64 + 32 + lr] = acc2[r];
        partial[row * 64 + 48 + lr] = acc3[r];
    }
}

// ---------------------------------------------------------------
// fold + OS-reduce, inverted mapping: one thread per OUTPUT element.
// No atomics, no memset.
// ---------------------------------------------------------------
__global__ __launch_bounds__(256) void fold_kernel(const float* __restrict__ partial,
                                                   float* __restrict__ out) {
    int gid = blockIdx.x * 256 + threadIdx.x;     // 131072 = 64*8*16*16
    int b = gid & 63, p = gid >> 6;
    int w = p & 15, h = (p >> 4) & 15, c = p >> 8;
    float sum = 0.0f;
#pragma unroll
    for (int ki = 0; ki < 3; ++ki) {
        int th = h + 1 - ki;
        if (th < 0 || (th & 1) || (th >> 1) >= 8) continue;
        int oh = th >> 1;
#pragma unroll
        for (int kj = 0; kj < 3; ++kj) {
            int tw = w + 1 - kj;
            if (tw < 0 || (tw & 1) || (tw >> 1) >= 8) continue;
            int ow = tw >> 1;
            int o = ((c * 3 + ki) * 3 + kj) * 64 + oh * 8 + ow;
            const float* pp = partial + (size_t)o * 64 + b;
#pragma unroll
            for (int osl = 0; osl < OS; ++osl)
                sum += pp[(size_t)osl * (OUT_F * 64)];
        }
    }
    out[((b * COUTC + c) * HOUTC + h) * WOUTC + w] = sum;
}

extern "C" void kernel_launch(void* const* d_in, const int* in_sizes, int n_in,
                              void* d_out, int out_size, void* d_ws, size_t ws_size,
                              hipStream_t stream) {
    const float* x  = (const float*)d_in[0];
    const float* Wb = (const float*)d_in[1];
    const float* Ws = (const float*)d_in[2];
    const float* Sc = (const float*)d_in[3];
    // d_in[4] = grid, recomputed analytically (uniform knots)

    float* out = (float*)d_out;

    __bf16* Abb     = (__bf16*)d_ws;                              // IN_F*64 bf16 (288 KB)
    __bf16* Bsb     = Abb + (size_t)IN_F * BATCH;                 // IN_F*64*8 bf16 (2.25 MB)
    float*  partial = (float*)(Bsb + (size_t)IN_F * BATCH * 8);   // OS*OUT_F*64 f32 (9.4 MB)

    prep_kernel<<<(IN_F * BATCH + 255) / 256, 256, 0, stream>>>(x, Abb, Bsb);

    gemm_kernel<<<(OUT_F / 48) * OS, 192, 0, stream>>>(Wb, Ws, Sc, Abb, Bsb, partial);

    fold_kernel<<<(BATCH * COUTC * HOUTC * WOUTC) / 256, 256, 0, stream>>>(partial, out);
}

// Round 15
// 104.095 us; speedup vs baseline: 1.4062x; 1.4062x over previous
//
#include <hip/hip_runtime.h>

// ---- problem constants ----
#define CIN   16
#define COUTC 8
#define HIN   8
#define WINW  8
#define SST   2
#define PPD   1
#define HOUTC 16
#define WOUTC 16
#define IN_F  2304   // CIN*3*3*4*4
#define OUT_F 4608   // COUT*3*3*8*8
#define BATCH 64

// ---- gemm decomposition ----
// Grid = (OUT_F/48) * OS = 96*8 = 768 = EXACTLY 3 blocks/CU (perfect balance).
// os = blockIdx % 8 == XCD (round-robin dispatch) -> act chunk L2-pinned.
#define OS    8             // K-splits
#define FC    (IN_F / OS)   // 288 f per block
#define SF    16            // f's per LDS subtile
#define NSUB  (FC / SF)     // 18 subtiles
#define NWAVE 3             // waves per block (48 o-rows)

typedef __bf16 bf16x8 __attribute__((ext_vector_type(8)));
typedef float  f32x4  __attribute__((ext_vector_type(4)));

// uniform knot grid: g[t] = (t-3)*0.4 - 1
__device__ __forceinline__ float gridv(int t) {
    return (float)(t - 3) * 0.4f - 1.0f;
}

// async global->LDS: per-lane global src, wave-uniform LDS base (+lane*16 by HW)
__device__ __forceinline__ void gload_lds16(const float* g, float* l) {
    __builtin_amdgcn_global_load_lds(
        (const __attribute__((address_space(1))) unsigned int*)g,
        (__attribute__((address_space(3))) unsigned int*)l, 16, 0, 0);
}

// ---------------------------------------------------------------
// prep: u = unfold(x); activations bf16 packed in lane-linear
// MFMA B-fragment chunks (1KB per (f-group, b-group) chunk).
//   spline: chunk C = (f>>2)*4 + (b>>4); slot = (f&3)*16 + (b&15)
//   base:   chunk C = (f>>5)*4 + (b>>4); slot = ((f>>3)&3)*16 + (b&15), elem f&7
// ---------------------------------------------------------------
__global__ __launch_bounds__(256) void prep_kernel(const float* __restrict__ x,
                                                   __bf16* __restrict__ Abb,
                                                   __bf16* __restrict__ Bsb) {
    int tid = blockIdx.x * 256 + threadIdx.x;   // tid = f*64 + b
    if (tid >= IN_F * BATCH) return;
    int f = tid >> 6, b = tid & 63;
    int ckk = f >> 4, s = f & 15;
    int c = ckk / 9, r = ckk % 9;
    int ki = r / 3, kj = r % 3;
    int oh = s >> 2, ow = s & 3;
    int h = ki + oh * SST - PPD;
    int w = kj + ow * SST - PPD;
    float u = 0.0f;
    if (h >= 0 && h < HIN && w >= 0 && w < WINW)
        u = x[((b * CIN + c) * HIN + h) * WINW + w];

    // base activation (silu)
    {
        size_t idx = ((size_t)((f >> 5) * 4 + (b >> 4))) * 512
                   + (((f >> 3) & 3) * 16 + (b & 15)) * 8 + (f & 7);
        Abb[idx] = (__bf16)(u / (1.0f + __expf(-u)));
    }

    // degree-3 B-spline bases (Cox-de Boor, matches reference)
    float bs[11];
#pragma unroll
    for (int t = 0; t < 11; ++t)
        bs[t] = (u >= gridv(t) && u < gridv(t + 1)) ? 1.0f : 0.0f;
#pragma unroll
    for (int k = 1; k <= 3; ++k) {
#pragma unroll
        for (int i = 0; i < 11; ++i) {
            if (i < 11 - k) {
                float g_i  = gridv(i);
                float g_ik = gridv(i + k);
                float g_i1 = gridv(i + 1);
                float g_k1 = gridv(i + k + 1);
                bs[i] = (u - g_i) / (g_ik - g_i) * bs[i]
                      + (g_k1 - u) / (g_k1 - g_i1) * bs[i + 1];
            }
        }
    }
    bf16x8 v;
#pragma unroll
    for (int t = 0; t < 8; ++t) v[t] = (__bf16)bs[t];
    size_t frag = ((size_t)((f >> 2) * 4 + (b >> 4))) * 64
                + (f & 3) * 16 + (b & 15);
    ((bf16x8*)Bsb)[frag] = v;
}

// ---------------------------------------------------------------
// MFMA GEMM. Weights fp32 streamed direct to registers (cvt bf16);
// activations + spline_scaler staged to LDS.
// Block: 3 waves x 16 DISJOINT o-rows = 48 o's, one shared K-chunk
// of FC f's. Wave: 16 o x 64 b. No cross-wave reduce.
// Grid 768 = 3 blocks/CU exactly; os == XCD.
// ---------------------------------------------------------------
__global__ __launch_bounds__(192, 2) void gemm_kernel(
    const float* __restrict__ Wb,    // (OUT_F, IN_F)
    const float* __restrict__ Ws,    // (OUT_F, IN_F, 8)
    const float* __restrict__ Sc,    // (OUT_F, IN_F)
    const __bf16* __restrict__ Abb,  // base B-frags (packed chunks)
    const __bf16* __restrict__ Bsb,  // spline B-frags (packed chunks)
    float* __restrict__ partial)     // (OS, OUT_F, 64)
{
    __shared__ __align__(16) char smem[2 * 16384 + 2 * 4096];   // 40 KB
    char* splb = smem;           // [2][16 KB] spline act subtile
    char* scb  = smem + 32768;   // [2][4 KB]  sc subtile [48 o][16 f] f32

    const int tid  = threadIdx.x;
    const int lane = tid & 63;
    const int wv   = tid >> 6;       // 0..2
    const int lr   = lane & 15;      // o-in-wave-tile / b-in-frag
    const int lg   = lane >> 4;      // k-group
    const int ot = blockIdx.x / OS;
    const int os = blockIdx.x % OS;  // == XCD under round-robin dispatch
    const int o0 = ot * 48;
    const int f0 = os * FC;
    const int o  = o0 + wv * 16 + lr;   // this lane's weight row

    f32x4 acc0 = {0.f,0.f,0.f,0.f}, acc1 = {0.f,0.f,0.f,0.f};
    f32x4 acc2 = {0.f,0.f,0.f,0.f}, acc3 = {0.f,0.f,0.f,0.f};

    // ---- stage subtile t into buffer pb ----
    // acts: 16 x 1KB chunks split over 3 waves (6/5/5); sc: 1KB per wave.
    auto stage = [&](int t, int pb) {
        const char* src = (const char*)Bsb + ((size_t)(f0 + t * SF) >> 2) * 4096;
        char* dst = splb + pb * 16384;
        for (int i = wv; i < 16; i += NWAVE)
            gload_lds16((const float*)(src + i * 1024) + lane * 4,
                        (float*)(dst + i * 1024));
        const int r = wv * 16 + (lane >> 2);
        gload_lds16(Sc + (size_t)(o0 + r) * IN_F + f0 + t * SF + (lane & 3) * 4,
                    (float*)(scb + pb * 4096 + wv * 1024));
    };

    const float* wp = Ws + ((size_t)o * IN_F + f0 + lg) * 8;

    stage(0, 0);
    __syncthreads();

    for (int t = 0; t < NSUB; ++t) {
        const int pb = t & 1;
        if (t + 1 < NSUB) stage(t + 1, pb ^ 1);

        const char*  ab  = splb + pb * 16384;
        const float* scl = (const float*)(scb + pb * 4096);
#pragma unroll
        for (int s = 0; s < SF / 4; ++s) {          // 4 K-steps
            const int fs = t * SF + s * 4;
            float4 w0 = *(const float4*)(wp + (size_t)fs * 8);
            float4 w1 = *(const float4*)(wp + (size_t)fs * 8 + 4);
            float  sc = scl[(wv * 16 + lr) * 16 + s * 4 + lg];
            bf16x8 b0 = *(const bf16x8*)(ab + s * 4096 +    0 + lane * 16);
            bf16x8 b1 = *(const bf16x8*)(ab + s * 4096 + 1024 + lane * 16);
            bf16x8 b2 = *(const bf16x8*)(ab + s * 4096 + 2048 + lane * 16);
            bf16x8 b3 = *(const bf16x8*)(ab + s * 4096 + 3072 + lane * 16);
            bf16x8 af;
            af[0] = (__bf16)(w0.x * sc); af[1] = (__bf16)(w0.y * sc);
            af[2] = (__bf16)(w0.z * sc); af[3] = (__bf16)(w0.w * sc);
            af[4] = (__bf16)(w1.x * sc); af[5] = (__bf16)(w1.y * sc);
            af[6] = (__bf16)(w1.z * sc); af[7] = (__bf16)(w1.w * sc);
            acc0 = __builtin_amdgcn_mfma_f32_16x16x32_bf16(af, b0, acc0, 0, 0, 0);
            acc1 = __builtin_amdgcn_mfma_f32_16x16x32_bf16(af, b1, acc1, 0, 0, 0);
            acc2 = __builtin_amdgcn_mfma_f32_16x16x32_bf16(af, b2, acc2, 0, 0, 0);
            acc3 = __builtin_amdgcn_mfma_f32_16x16x32_bf16(af, b3, acc3, 0, 0, 0);
        }
        __syncthreads();   // drains stage(t+1), guards buffer reuse
    }

    // ---- base GEMM: FC/32 = 9 K-steps, acts direct from global (L2-hot) ----
    const float*  wbp = Wb + (size_t)o * IN_F + f0 + lg * 8;
    const bf16x8* ap  = (const bf16x8*)Abb + ((size_t)f0 >> 5) * 256 + lane;
#pragma unroll
    for (int s = 0; s < FC / 32; ++s) {
        float4 w0 = *(const float4*)(wbp + s * 32);
        float4 w1 = *(const float4*)(wbp + s * 32 + 4);
        bf16x8 b0 = ap[s * 256 +   0];
        bf16x8 b1 = ap[s * 256 +  64];
        bf16x8 b2 = ap[s * 256 + 128];
        bf16x8 b3 = ap[s * 256 + 192];
        bf16x8 af;
        af[0] = (__bf16)w0.x; af[1] = (__bf16)w0.y;
        af[2] = (__bf16)w0.z; af[3] = (__bf16)w0.w;
        af[4] = (__bf16)w1.x; af[5] = (__bf16)w1.y;
        af[6] = (__bf16)w1.z; af[7] = (__bf16)w1.w;
        acc0 = __builtin_amdgcn_mfma_f32_16x16x32_bf16(af, b0, acc0, 0, 0, 0);
        acc1 = __builtin_amdgcn_mfma_f32_16x16x32_bf16(af, b1, acc1, 0, 0, 0);
        acc2 = __builtin_amdgcn_mfma_f32_16x16x32_bf16(af, b2, acc2, 0, 0, 0);
        acc3 = __builtin_amdgcn_mfma_f32_16x16x32_bf16(af, b3, acc3, 0, 0, 0);
    }

    // ---- epilogue: waves own disjoint o's -> direct coalesced store ----
    // D layout: lane holds D[lg*4 + r][lr]; b = j*16 + lr
#pragma unroll
    for (int r = 0; r < 4; ++r) {
        const size_t row = (size_t)os * OUT_F + o0 + wv * 16 + lg * 4 + r;
        partial[row * 64 +  0 + lr] = acc0[r];
        partial[row * 64 + 16 + lr] = acc1[r];
        partial[row * 64 + 32 + lr] = acc2[r];
        partial[row * 64 + 48 + lr] = acc3[r];
    }
}

// ---------------------------------------------------------------
// fold + OS-reduce, inverted mapping: one thread per OUTPUT element.
// No atomics, no memset.
// ---------------------------------------------------------------
__global__ __launch_bounds__(256) void fold_kernel(const float* __restrict__ partial,
                                                   float* __restrict__ out) {
    int gid = blockIdx.x * 256 + threadIdx.x;     // 131072 = 64*8*16*16
    int b = gid & 63, p = gid >> 6;
    int w = p & 15, h = (p >> 4) & 15, c = p >> 8;
    float sum = 0.0f;
#pragma unroll
    for (int ki = 0; ki < 3; ++ki) {
        int th = h + 1 - ki;
        if (th < 0 || (th & 1) || (th >> 1) >= 8) continue;
        int oh = th >> 1;
#pragma unroll
        for (int kj = 0; kj < 3; ++kj) {
            int tw = w + 1 - kj;
            if (tw < 0 || (tw & 1) || (tw >> 1) >= 8) continue;
            int ow = tw >> 1;
            int o = ((c * 3 + ki) * 3 + kj) * 64 + oh * 8 + ow;
            const float* pp = partial + (size_t)o * 64 + b;
#pragma unroll
            for (int osl = 0; osl < OS; ++osl)
                sum += pp[(size_t)osl * (OUT_F * 64)];
        }
    }
    out[((b * COUTC + c) * HOUTC + h) * WOUTC + w] = sum;
}

extern "C" void kernel_launch(void* const* d_in, const int* in_sizes, int n_in,
                              void* d_out, int out_size, void* d_ws, size_t ws_size,
                              hipStream_t stream) {
    const float* x  = (const float*)d_in[0];
    const float* Wb = (const float*)d_in[1];
    const float* Ws = (const float*)d_in[2];
    const float* Sc = (const float*)d_in[3];
    // d_in[4] = grid, recomputed analytically (uniform knots)

    float* out = (float*)d_out;

    __bf16* Abb     = (__bf16*)d_ws;                              // IN_F*64 bf16 (288 KB)
    __bf16* Bsb     = Abb + (size_t)IN_F * BATCH;                 // IN_F*64*8 bf16 (2.25 MB)
    float*  partial = (float*)(Bsb + (size_t)IN_F * BATCH * 8);   // OS*OUT_F*64 f32 (9.4 MB)

    prep_kernel<<<(IN_F * BATCH + 255) / 256, 256, 0, stream>>>(x, Abb, Bsb);

    gemm_kernel<<<(OUT_F / 48) * OS, 192, 0, stream>>>(Wb, Ws, Sc, Abb, Bsb, partial);

    fold_kernel<<<(BATCH * COUTC * HOUTC * WOUTC) / 256, 256, 0, stream>>>(partial, out);
}